// Round 3
// baseline (1496.198 us; speedup 1.0000x reference)
//
#include <hip/hip_runtime.h>

typedef unsigned int uint;
typedef unsigned short ushort;

#define N_NODES 2000
#define N_EDGES 32000
#define PER 576
#define WNUM 2304

// ---------- ws layout (float element offsets) — total 672,004 bytes ----------
constexpr size_t OFF_AGG0 = 0;        // 2000*32  (raw: sum of ex*v0)
constexpr size_t OFF_AGG1 = 64000;    // 2000*48  (raw: sum of ex*v1)
constexpr size_t OFF_DEN  = 160000;   // 2000*4   (sum of ex)
constexpr size_t OFF_FLAG = 168000;   // 1 int: 1 = inputs are f32, 0 = bf16

__device__ __forceinline__ float b2f(ushort u){ union{uint i; float f;}x; x.i=((uint)u)<<16; return x.f; }
__device__ __forceinline__ float lo16(uint w){ union{uint u; float f;}x; x.u=w<<16; return x.f; }
__device__ __forceinline__ float hi16(uint w){ union{uint u; float f;}x; x.u=w&0xFFFF0000u; return x.f; }
__device__ __forceinline__ ushort f2b(float f){
  union{float f; uint u;}x; x.f=f;
  uint r = (x.u + 0x7FFFu + ((x.u>>16)&1u)) >> 16;
  return (ushort)r;
}
__device__ __forceinline__ float siluf(float x){ return x / (1.f + __expf(-x)); }
// dtype-dispatched scalar load
__device__ __forceinline__ float ldf(const void* p, int i, bool f32){
  return f32 ? ((const float*)p)[i] : b2f(((const ushort*)p)[i]);
}

// ---------- K0: dtype probe ----------
// bf16 N(0,1) data: exponent field of any halfword <= ~0x82. If the buffer is
// really f32, even halfwords are mantissa bits -> exp field ~uniform -> ~37% >= 0xA0.
__global__ void probe_kernel(const ushort* __restrict__ nf, int* __restrict__ flag){
  __shared__ int cnt;
  if (threadIdx.x == 0) cnt = 0;
  __syncthreads();
  uint u = nf[threadIdx.x * 2];          // even halfword indices 0..510
  uint ex = (u >> 7) & 0xFFu;
  if (ex >= 0xA0u) atomicAdd(&cnt, 1);
  __syncthreads();
  if (threadIdx.x == 0) *flag = (cnt >= 20) ? 1 : 0;
}

// ---------- K1: fused edge kernel: q-recompute + radial MLP + TP + logits + exp + aggregation ----------
// Softmax uses FIXED max = 10.0 (logits clipped to [-10,10]) -> identical to segment-max version.
#define ET 8
__global__ __launch_bounds__(256) void edge_kernel(
    const void* __restrict__ nf,  const int* __restrict__ eidx,
    const void* __restrict__ esh, const void* __restrict__ emb,
    const void* __restrict__ Wk1, const void* __restrict__ bk1,
    const void* __restrict__ Wk2, const void* __restrict__ bk2,
    const void* __restrict__ Wv1, const void* __restrict__ bv1,
    const void* __restrict__ Wv2, const void* __restrict__ bv2,
    const void* __restrict__ Wq0, const void* __restrict__ Wq1,
    const void* __restrict__ Wd0, const void* __restrict__ Wd1,
    float* __restrict__ agg0, float* __restrict__ agg1, float* __restrict__ denom,
    const int* __restrict__ flag){
  __shared__ float hidk[ET][64], hidv[ET][64];
  __shared__ float fss[ET][32], fvv[ET][16], ssl[ET][32], vsh[ET][48], sh1l[ET][3];
  __shared__ float sdl[ET][32], vdl[ET][48];          // dst node features
  __shared__ float q0t[ET][32], qd0l[ET][32];         // q0, q0@Wd0 per head
  __shared__ float q1t[ET][48], qd1l[ET][48];         // q1, q1@Wd1 per head [h][w/v][i]
  // accs per edge: [0,32) k0 | [32,64) v0 | [64,80) psv_k | [80,96) psv_v | [96,144) vs_k->k1 | [144,192) vs_v
  __shared__ float accs[ET][192];
  __shared__ int dstl[ET];

  const bool F32 = (*flag) != 0;
  const int t  = threadIdx.x;
  const int es = t >> 5;
  const int r  = t & 31;
  const int e  = blockIdx.x*ET + es;

  // ---- Phase A: per-edge features (src + dst) ----
  const int src = eidx[e];
  const int dst = eidx[N_EDGES + e];
  if (r == 0) dstl[es] = dst;
  const float sh0 = ldf(esh, e*4+0, F32);
  const float s1a = ldf(esh, e*4+1, F32), s1b = ldf(esh, e*4+2, F32), s1c = ldf(esh, e*4+3, F32);
  if (r == 0){ sh1l[es][0]=s1a; sh1l[es][1]=s1b; sh1l[es][2]=s1c; }
  {
    float sv = ldf(nf, src*80 + r, F32);
    ssl[es][r] = sv;
    fss[es][r] = sv * sh0;
    sdl[es][r] = ldf(nf, dst*80 + r, F32);
  }
  if (r < 16){
    float v0 = ldf(nf, src*80 + 32 + r*3 + 0, F32);
    float v1 = ldf(nf, src*80 + 32 + r*3 + 1, F32);
    float v2 = ldf(nf, src*80 + 32 + r*3 + 2, F32);
    vsh[es][r*3+0] = v0*sh0; vsh[es][r*3+1] = v1*sh0; vsh[es][r*3+2] = v2*sh0;
    fvv[es][r] = (v0*s1a + v1*s1b + v2*s1c) * 0.5773502691896258f;  // 1/sqrt(3)
    vdl[es][r*3+0] = ldf(nf, dst*80 + 32 + r*3 + 0, F32);
    vdl[es][r*3+1] = ldf(nf, dst*80 + 32 + r*3 + 1, F32);
    vdl[es][r*3+2] = ldf(nf, dst*80 + 32 + r*3 + 2, F32);
  }
  for (int idx=r; idx<192; idx+=32) accs[es][idx] = 0.f;

  // ---- Phase A2: q for dst node (all within one wave -> lockstep ordering; barrier below anyway) ----
  {
    const int h = r >> 3, w = r & 7;
    float a = 0.f;
    #pragma unroll
    for (int u=0; u<32; ++u) a += sdl[es][u]*ldf(Wq0, h*256 + u*8 + w, F32);
    q0t[es][r] = a * 0.17677669529663687f;  // 1/sqrt(32)
  }
  {
    const int h = r >> 3, v = r & 7;
    float a = 0.f;
    #pragma unroll
    for (int u=0; u<8; ++u) a += q0t[es][h*8+u]*ldf(Wd0, u*8+v, F32);
    qd0l[es][r] = a;
  }
  if (r < 16){
    const int h = r >> 2, w = r & 3;
    #pragma unroll
    for (int i=0; i<3; ++i){
      float a = 0.f;
      #pragma unroll
      for (int u=0; u<16; ++u) a += vdl[es][u*3+i]*ldf(Wq1, h*64 + u*4 + w, F32);
      q1t[es][r*3+i] = a * 0.25f;  // 1/sqrt(16)
    }
    #pragma unroll
    for (int i=0; i<3; ++i){
      float a = 0.f;
      #pragma unroll
      for (int u=0; u<4; ++u) a += q1t[es][((h*4+u))*3+i]*ldf(Wd1, u*4+w, F32);
      qd1l[es][r*3+i] = a;       // layout [h][v][i] == [h*12 + v*3 + i]
    }
  }

  // ---- Phase B: radial-MLP hidden layers ----
  {
    float em[16];
    #pragma unroll
    for (int b=0; b<16; ++b) em[b] = ldf(emb, e*16 + b, F32);
    #pragma unroll
    for (int cc=0; cc<2; ++cc){
      int c = r + cc*32;
      float ak = ldf(bk1, c, F32), av = ldf(bv1, c, F32);
      #pragma unroll
      for (int b=0; b<16; ++b){
        float x = em[b];
        ak += x * ldf(Wk1, b*64 + c, F32);
        av += x * ldf(Wv1, b*64 + c, F32);
      }
      hidk[es][c] = siluf(ak);
      hidv[es][c] = siluf(av);
    }
  }
  __syncthreads();

  // ---- Phase C: weight-gen GEMV fused with TP contraction (LDS-atomic scatter) ----
  const float* hkrow = &hidk[es][0];
  const float* hvrow = &hidv[es][0];
  for (int chunk=0; chunk<9; ++chunk){
    const int jbase = chunk*256 + r*8;
    float wk[8], wv[8];
    if (F32){
      const float* bk2f = (const float*)bk2 + jbase;
      const float* bv2f = (const float*)bv2 + jbase;
      #pragma unroll
      for (int q=0; q<8; ++q){ wk[q]=bk2f[q]; wv[q]=bv2f[q]; }
      const float* w2kp = (const float*)Wk2 + jbase;
      const float* w2vp = (const float*)Wv2 + jbase;
      #pragma unroll 4
      for (int c=0; c<64; ++c){
        float4 a0 = *(const float4*)(w2kp + (size_t)c*WNUM);
        float4 a1 = *(const float4*)(w2kp + (size_t)c*WNUM + 4);
        float4 b0 = *(const float4*)(w2vp + (size_t)c*WNUM);
        float4 b1 = *(const float4*)(w2vp + (size_t)c*WNUM + 4);
        float hk = hkrow[c], hv = hvrow[c];
        wk[0]+=hk*a0.x; wk[1]+=hk*a0.y; wk[2]+=hk*a0.z; wk[3]+=hk*a0.w;
        wk[4]+=hk*a1.x; wk[5]+=hk*a1.y; wk[6]+=hk*a1.z; wk[7]+=hk*a1.w;
        wv[0]+=hv*b0.x; wv[1]+=hv*b0.y; wv[2]+=hv*b0.z; wv[3]+=hv*b0.w;
        wv[4]+=hv*b1.x; wv[5]+=hv*b1.y; wv[6]+=hv*b1.z; wv[7]+=hv*b1.w;
      }
    } else {
      uint4 bkv = *((const uint4*)((const ushort*)bk2 + jbase));
      uint4 bvv = *((const uint4*)((const ushort*)bv2 + jbase));
      wk[0]=lo16(bkv.x); wk[1]=hi16(bkv.x); wk[2]=lo16(bkv.y); wk[3]=hi16(bkv.y);
      wk[4]=lo16(bkv.z); wk[5]=hi16(bkv.z); wk[6]=lo16(bkv.w); wk[7]=hi16(bkv.w);
      wv[0]=lo16(bvv.x); wv[1]=hi16(bvv.x); wv[2]=lo16(bvv.y); wv[3]=hi16(bvv.y);
      wv[4]=lo16(bvv.z); wv[5]=hi16(bvv.z); wv[6]=lo16(bvv.w); wv[7]=hi16(bvv.w);
      const ushort* w2kp = (const ushort*)Wk2 + jbase;
      const ushort* w2vp = (const ushort*)Wv2 + jbase;
      #pragma unroll 4
      for (int c=0; c<64; ++c){
        uint4 ak = *(const uint4*)(w2kp + (size_t)c*WNUM);
        uint4 av = *(const uint4*)(w2vp + (size_t)c*WNUM);
        float hk = hkrow[c], hv = hvrow[c];
        wk[0]+=hk*lo16(ak.x); wk[1]+=hk*hi16(ak.x); wk[2]+=hk*lo16(ak.y); wk[3]+=hk*hi16(ak.y);
        wk[4]+=hk*lo16(ak.z); wk[5]+=hk*hi16(ak.z); wk[6]+=hk*lo16(ak.w); wk[7]+=hk*hi16(ak.w);
        wv[0]+=hv*lo16(av.x); wv[1]+=hv*hi16(av.x); wv[2]+=hv*lo16(av.y); wv[3]+=hv*hi16(av.y);
        wv[4]+=hv*lo16(av.z); wv[5]+=hv*hi16(av.z); wv[6]+=hv*lo16(av.w); wv[7]+=hv*hi16(av.w);
      }
    }
    const int h  = jbase / PER;
    const int rl = jbase - h*PER;
    if (rl < 256){            // Wss: feat = ss*sh0 -> out0[h][w]
      const float f = fss[es][rl>>3];
      #pragma unroll
      for (int q=0; q<8; ++q){
        atomicAdd(&accs[es][h*8+q],    f*wk[q]);
        atomicAdd(&accs[es][32+h*8+q], f*wv[q]);
      }
    } else if (rl < 384){     // Wvv: feat = vv.sh1/sqrt3 -> out0[h][w]
      const float f = fvv[es][(rl-256)>>3];
      #pragma unroll
      for (int q=0; q<8; ++q){
        atomicAdd(&accs[es][h*8+q],    f*wk[q]);
        atomicAdd(&accs[es][32+h*8+q], f*wv[q]);
      }
    } else if (rl < 512){     // Wsv: feat = ss -> psv[h][w]
      const int u0 = (rl-384)>>2;
      #pragma unroll
      for (int q=0; q<8; ++q){
        const float f = ssl[es][u0 + (q>>2)];
        const int w = q & 3;
        atomicAdd(&accs[es][64+h*4+w], f*wk[q]);
        atomicAdd(&accs[es][80+h*4+w], f*wv[q]);
      }
    } else {                  // Wvs: feat = vv*sh0 per i -> out1[h][w][i]
      const int u0 = (rl-512)>>2;
      #pragma unroll
      for (int q=0; q<8; ++q){
        const int u = u0 + (q>>2), w = q & 3;
        #pragma unroll
        for (int i=0; i<3; ++i){
          const float f = vsh[es][u*3+i];
          atomicAdd(&accs[es][96+h*12+w*3+i],  f*wk[q]);
          atomicAdd(&accs[es][144+h*12+w*3+i], f*wv[q]);
        }
      }
    }
  }
  __syncthreads();

  // ---- Phase D1: finalize k1 in LDS region [96,144) ----
  const float invfan = 0.14433756729740643f;  // 1/sqrt(48)
  for (int idx=r; idx<48; idx+=32){
    int hh = idx/12, rem = idx - hh*12, w = rem/3, i = rem - w*3;
    accs[es][96+idx] = (accs[es][64+hh*4+w]*sh1l[es][i] + accs[es][96+idx]) * invfan;
  }
  __syncthreads();

  // ---- Phase D2: logits -> ex -> global aggregation (one lane per head) ----
  if (r < 4){
    const int hh = r, d = dstl[es];
    float lg = 0.f;
    #pragma unroll
    for (int w=0; w<8; ++w) lg += qd0l[es][hh*8+w]*(accs[es][hh*8+w]*invfan);
    float lg1 = 0.f;
    #pragma unroll
    for (int idx=0; idx<12; ++idx) lg1 += qd1l[es][hh*12+idx]*accs[es][96+hh*12+idx];
    lg = (lg + lg1*0.5773502691896258f) * 0.025f;  // 1/(sqrt(80)*sqrt(20))
    lg = fminf(10.f, fmaxf(-10.f, lg));
    const float exv = __expf(lg - 10.0f);          // fixed max = 10
    atomicAdd(denom + d*4+hh, exv);
    #pragma unroll
    for (int w=0; w<8; ++w)
      atomicAdd(agg0 + d*32 + hh*8 + w, exv * accs[es][32+hh*8+w]*invfan);
    #pragma unroll
    for (int w=0; w<4; ++w)
      #pragma unroll
      for (int i=0; i<3; ++i){
        float v1 = (accs[es][80+hh*4+w]*sh1l[es][i] + accs[es][144+hh*12+w*3+i]) * invfan;
        atomicAdd(agg1 + d*48 + hh*12 + w*3 + i, exv * v1);
      }
  }
}

// ---------- K2: per-node output MLP (divides raw agg by denom) ----------
__global__ __launch_bounds__(64) void node_out_kernel(
    const void* __restrict__ nf, const float* __restrict__ agg0r, const float* __restrict__ agg1r,
    const float* __restrict__ denom,
    const void* __restrict__ Wo0, const void* __restrict__ Wo1,
    const void* __restrict__ Wf10, const void* __restrict__ Wf11,
    const void* __restrict__ Wf20, const void* __restrict__ Wf21,
    void* __restrict__ out, const int* __restrict__ flag){
  __shared__ float ag0[32], ag1[48], adiv[4];
  __shared__ float x0s[32], x1s[48], a0s[64], f1s[48], coefs[16];
  const bool F32 = (*flag) != 0;
  const int n = blockIdx.x, t = threadIdx.x;
  if (t < 4) adiv[t] = 1.f / (denom[n*4+t] + 1e-12f);
  __syncthreads();
  if (t < 32) ag0[t] = agg0r[n*32+t] * adiv[t>>3];
  if (t < 48) ag1[t] = agg1r[n*48+t] * adiv[t/12];
  __syncthreads();
  if (t < 32){
    float o = 0.f;
    #pragma unroll
    for (int k=0; k<32; ++k) o += ag0[k]*ldf(Wo0, k*32+t, F32);
    x0s[t] = ldf(nf, n*80+t, F32) + o*0.17677669529663687f;  // 1/sqrt(32)
  }
  if (t < 48){
    int w = t/3, i = t - w*3;
    float o = 0.f;
    #pragma unroll
    for (int u=0; u<16; ++u) o += ag1[u*3+i]*ldf(Wo1, u*16+w, F32);
    x1s[t] = ldf(nf, n*80+32+t, F32) + o*0.25f;  // 1/sqrt(16)
  }
  __syncthreads();
  {
    float f0 = 0.f;
    #pragma unroll
    for (int u=0; u<32; ++u) f0 += x0s[u]*ldf(Wf10, u*64+t, F32);
    a0s[t] = siluf(f0*0.17677669529663687f);
  }
  if (t < 48){
    int w = t/3, i = t - w*3;
    float f1 = 0.f;
    #pragma unroll
    for (int u=0; u<16; ++u) f1 += x1s[u*3+i]*ldf(Wf11, u*16+w, F32);
    f1s[t] = f1*0.25f;
  }
  __syncthreads();
  if (t < 16){
    float a = f1s[t*3], b = f1s[t*3+1], c = f1s[t*3+2];
    float nrm = sqrtf(a*a+b*b+c*c);
    float safe = fmaxf(nrm, 1e-8f);
    coefs[t] = (nrm < 1e-8f) ? 0.f : siluf(nrm)/safe;
  }
  __syncthreads();
  if (t < 32){
    float g = 0.f;
    #pragma unroll
    for (int u=0; u<64; ++u) g += a0s[u]*ldf(Wf20, u*32+t, F32);
    float val = x0s[t] + g*0.125f;  // 1/sqrt(64)
    if (F32) ((float*)out)[n*80+t] = val; else ((ushort*)out)[n*80+t] = f2b(val);
  }
  if (t < 48){
    int w = t/3, i = t - w*3;
    float g = 0.f;
    #pragma unroll
    for (int u=0; u<16; ++u) g += coefs[u]*f1s[u*3+i]*ldf(Wf21, u*16+w, F32);
    float val = x1s[t] + g*0.25f;
    if (F32) ((float*)out)[n*80+32+t] = val; else ((ushort*)out)[n*80+32+t] = f2b(val);
  }
}

extern "C" void kernel_launch(void* const* d_in, const int* in_sizes, int n_in,
                              void* d_out, int out_size, void* d_ws, size_t ws_size,
                              hipStream_t stream){
  const void* nf   = d_in[0];
  const int*  eidx = (const int*)d_in[1];
  const void* esh  = d_in[2];
  const void* emb  = d_in[3];
  const void* Wq0  = d_in[4];
  const void* Wq1  = d_in[5];
  const void* Wk1  = d_in[6];
  const void* bk1  = d_in[7];
  const void* Wk2  = d_in[8];
  const void* bk2  = d_in[9];
  const void* Wv1  = d_in[10];
  const void* bv1  = d_in[11];
  const void* Wv2  = d_in[12];
  const void* bv2  = d_in[13];
  const void* Wd0  = d_in[14];
  const void* Wd1  = d_in[15];
  const void* Wo0  = d_in[16];
  const void* Wo1  = d_in[17];
  const void* Wf10 = d_in[18];
  const void* Wf11 = d_in[19];
  const void* Wf20 = d_in[20];
  const void* Wf21 = d_in[21];
  float* ws = (float*)d_ws;

  float* agg0  = ws + OFF_AGG0;
  float* agg1  = ws + OFF_AGG1;
  float* denom = ws + OFF_DEN;
  int*   flag  = (int*)(ws + OFF_FLAG);

  hipMemsetAsync(agg0, 0, (64000+96000+8000)*sizeof(float), stream);
  probe_kernel<<<1, 256, 0, stream>>>((const ushort*)nf, flag);
  edge_kernel<<<N_EDGES/ET, 256, 0, stream>>>(nf, eidx, esh, emb, Wk1, bk1, Wk2, bk2,
                                              Wv1, bv1, Wv2, bv2, Wq0, Wq1, Wd0, Wd1,
                                              agg0, agg1, denom, flag);
  node_out_kernel<<<N_NODES, 64, 0, stream>>>(nf, agg0, agg1, denom,
                                              Wo0, Wo1, Wf10, Wf11, Wf20, Wf21, d_out, flag);
}

// Round 4
// 558.215 us; speedup vs baseline: 2.6803x; 2.6803x over previous
//
#include <hip/hip_runtime.h>

typedef unsigned int uint;
typedef unsigned short ushort;

#define N_NODES 2000
#define N_EDGES 32000
#define WNUM 2304

// ---------- ws layout (float element offsets) ----------
constexpr size_t OFF_AGG0 = 0;        // 2000*32
constexpr size_t OFF_AGG1 = 64000;    // 2000*48
constexpr size_t OFF_DEN  = 160000;   // 2000*4
constexpr size_t OFF_FLAG = 168000;   // 1 int: 1 = f32 inputs, 0 = bf16

__device__ __forceinline__ float b2f(ushort u){ union{uint i; float f;}x; x.i=((uint)u)<<16; return x.f; }
__device__ __forceinline__ float lo16(uint w){ union{uint u; float f;}x; x.u=w<<16; return x.f; }
__device__ __forceinline__ float hi16(uint w){ union{uint u; float f;}x; x.u=w&0xFFFF0000u; return x.f; }
__device__ __forceinline__ ushort f2b(float f){
  union{float f; uint u;}x; x.f=f;
  uint r = (x.u + 0x7FFFu + ((x.u>>16)&1u)) >> 16;
  return (ushort)r;
}
__device__ __forceinline__ float siluf(float x){ return x / (1.f + __expf(-x)); }

template<bool F32>
__device__ __forceinline__ float ldf(const void* p, int i){
  if (F32) return ((const float*)p)[i];
  return b2f(((const ushort*)p)[i]);
}
__device__ __forceinline__ float ldfr(const void* p, int i, bool f32){
  return f32 ? ((const float*)p)[i] : b2f(((const ushort*)p)[i]);
}

// load 8 consecutive elements (16B-aligned group) as f32
template<bool F32>
__device__ __forceinline__ void load8(const void* p, size_t off, float w[8]){
  if (F32){
    const float4* q = (const float4*)((const float*)p + off);
    float4 a = q[0], b = q[1];
    w[0]=a.x; w[1]=a.y; w[2]=a.z; w[3]=a.w; w[4]=b.x; w[5]=b.y; w[6]=b.z; w[7]=b.w;
  } else {
    uint4 a = *(const uint4*)((const ushort*)p + off);
    w[0]=lo16(a.x); w[1]=hi16(a.x); w[2]=lo16(a.y); w[3]=hi16(a.y);
    w[4]=lo16(a.z); w[5]=hi16(a.z); w[6]=lo16(a.w); w[7]=hi16(a.w);
  }
}

// butterfly reduction over 32-lane segments
template<int NV, int NSTEP>
__device__ __forceinline__ void bfly(float* v){
  #pragma unroll
  for (int s=0; s<NSTEP; ++s){
    #pragma unroll
    for (int i=0; i<NV; ++i) v[i] += __shfl_xor(v[i], 1<<s, 32);
  }
}

// weight-gen GEMV: 8 weights at j0, shared across 4 edges of this half-wave
template<bool F32>
__device__ __forceinline__ void gemv8(const void* Wk2, const void* Wv2,
    const void* bk2, const void* bv2, const float* hidbase,
    int j0, float wk[4][8], float wv[4][8]){
  float tk[8], tv[8];
  load8<F32>(bk2, j0, tk);
  load8<F32>(bv2, j0, tv);
  #pragma unroll
  for (int e=0; e<4; ++e)
    #pragma unroll
    for (int q=0; q<8; ++q){ wk[e][q]=tk[q]; wv[e][q]=tv[q]; }
  #pragma unroll 2
  for (int c=0; c<64; ++c){
    load8<F32>(Wk2, (size_t)c*WNUM + j0, tk);
    load8<F32>(Wv2, (size_t)c*WNUM + j0, tv);
    #pragma unroll
    for (int e=0; e<4; ++e){
      const float2 h2 = *(const float2*)(hidbase + e*128 + c*2);
      #pragma unroll
      for (int q=0; q<8; ++q){ wk[e][q] += h2.x*tk[q]; wv[e][q] += h2.y*tv[q]; }
    }
  }
}

// ---------- K0: dtype probe ----------
__global__ void probe_kernel(const ushort* __restrict__ nf, int* __restrict__ flag){
  __shared__ int cnt;
  if (threadIdx.x == 0) cnt = 0;
  __syncthreads();
  uint u = nf[threadIdx.x * 2];
  uint ex = (u >> 7) & 0xFFu;
  if (ex >= 0xA0u) atomicAdd(&cnt, 1);
  __syncthreads();
  if (threadIdx.x == 0) *flag = (cnt >= 20) ? 1 : 0;
}

// accs region offsets (per edge, 256 floats)
#define K0SS 0
#define V0SS 32
#define K0VV 64
#define V0VV 96
#define PSVK 128
#define PSVV 144
#define VSK  160
#define VSV  208

struct Smem {
  float hidkv[32][128];   // [le][c*2 + {k,v}]
  float fss[32][32];
  float fvv[32][16];
  float ssl[32][32];
  float vsh[32][48];
  float sh1l[32][3];
  float qd0l[32][32];
  float qd1l[32][48];
  float accs[32][256];    // dual use: [0..80) dst features during A->A2
  float sh_ex[32][4];
  int   dstl[32];
};

template<bool F32>
__device__ void edge_body(
    const void* __restrict__ nf,  const int* __restrict__ eidx,
    const void* __restrict__ esh, const void* __restrict__ emb,
    const void* __restrict__ Wk1, const void* __restrict__ bk1,
    const void* __restrict__ Wk2, const void* __restrict__ bk2,
    const void* __restrict__ Wv1, const void* __restrict__ bv1,
    const void* __restrict__ Wv2, const void* __restrict__ bv2,
    const void* __restrict__ Wq0, const void* __restrict__ Wq1,
    const void* __restrict__ Wd0, const void* __restrict__ Wd1,
    float* __restrict__ agg0, float* __restrict__ agg1, float* __restrict__ denom,
    Smem& sm){
  const int t  = threadIdx.x;
  const int hw = t >> 5;
  const int r  = t & 31;
  const int le0 = hw*4;
  const int geb = blockIdx.x*32;

  // ---- Phase A: per-edge features, dst features into accs scratch ----
  #pragma unroll 1
  for (int e=0; e<4; ++e){
    const int le = le0+e, ge = geb+le;
    const int src = eidx[ge], d = eidx[N_EDGES+ge];
    const float sh0 = ldf<F32>(esh, ge*4+0);
    if (r == 0){
      sm.dstl[le] = d;
      sm.sh1l[le][0] = ldf<F32>(esh, ge*4+1);
      sm.sh1l[le][1] = ldf<F32>(esh, ge*4+2);
      sm.sh1l[le][2] = ldf<F32>(esh, ge*4+3);
    }
    float sv = ldf<F32>(nf, src*80 + r);
    sm.ssl[le][r] = sv;
    sm.fss[le][r] = sv * sh0;
    sm.accs[le][r] = ldf<F32>(nf, d*80 + r);         // dst scalar feats
    if (r < 16){
      float s1a = ldf<F32>(esh, ge*4+1), s1b = ldf<F32>(esh, ge*4+2), s1c = ldf<F32>(esh, ge*4+3);
      float v0 = ldf<F32>(nf, src*80+32+r*3+0);
      float v1 = ldf<F32>(nf, src*80+32+r*3+1);
      float v2 = ldf<F32>(nf, src*80+32+r*3+2);
      sm.vsh[le][r*3+0] = v0*sh0; sm.vsh[le][r*3+1] = v1*sh0; sm.vsh[le][r*3+2] = v2*sh0;
      sm.fvv[le][r] = (v0*s1a + v1*s1b + v2*s1c) * 0.5773502691896258f;
      sm.accs[le][32+r*3+0] = ldf<F32>(nf, d*80+32+r*3+0);   // dst vector feats
      sm.accs[le][32+r*3+1] = ldf<F32>(nf, d*80+32+r*3+1);
      sm.accs[le][32+r*3+2] = ldf<F32>(nf, d*80+32+r*3+2);
    }
  }

  // ---- Phase B: radial-MLP hidden layers -> hidkv ----
  #pragma unroll 1
  for (int e=0; e<4; ++e){
    const int le = le0+e, ge = geb+le;
    float em[16];
    #pragma unroll
    for (int b=0; b<16; ++b) em[b] = ldf<F32>(emb, ge*16 + b);
    #pragma unroll
    for (int cc=0; cc<2; ++cc){
      const int c = r + cc*32;
      float ak = ldf<F32>(bk1, c), av = ldf<F32>(bv1, c);
      #pragma unroll
      for (int b=0; b<16; ++b){
        ak += em[b] * ldf<F32>(Wk1, b*64 + c);
        av += em[b] * ldf<F32>(Wv1, b*64 + c);
      }
      sm.hidkv[le][c*2+0] = siluf(ak);
      sm.hidkv[le][c*2+1] = siluf(av);
    }
  }
  __syncthreads();

  // ---- Phase A2: dst q (Wd folded): qd0l, qd1l ----
  #pragma unroll 1
  for (int e=0; e<4; ++e){
    const int le = le0+e;
    const int h8 = r & 24;      // h*8
    const int w8 = r & 7;
    float a = 0.f;
    #pragma unroll
    for (int u=0; u<32; ++u) a += sm.accs[le][u] * ldf<F32>(Wq0, (r>>3)*256 + u*8 + w8);
    const float q0 = a * 0.17677669529663687f;    // 1/sqrt(32)
    float qd0 = 0.f;
    #pragma unroll
    for (int u=0; u<8; ++u) qd0 += __shfl(q0, h8+u, 32) * ldf<F32>(Wd0, u*8 + w8);
    sm.qd0l[le][r] = qd0;

    const int rr = r & 15, h4 = rr>>2, w4 = rr&3;
    float q1i[3];
    #pragma unroll
    for (int i=0; i<3; ++i){
      float b = 0.f;
      #pragma unroll
      for (int u=0; u<16; ++u) b += sm.accs[le][32+u*3+i] * ldf<F32>(Wq1, h4*64 + u*4 + w4);
      q1i[i] = b * 0.25f;       // 1/sqrt(16)
    }
    float qd1[3];
    #pragma unroll
    for (int i=0; i<3; ++i){
      float b = 0.f;
      #pragma unroll
      for (int u=0; u<4; ++u) b += __shfl(q1i[i], h4*4+u, 32) * ldf<F32>(Wd1, u*4 + w4);
      qd1[i] = b;
    }
    if (r < 16){
      sm.qd1l[le][rr*3+0] = qd1[0];
      sm.qd1l[le][rr*3+1] = qd1[1];
      sm.qd1l[le][rr*3+2] = qd1[2];
    }
  }
  __syncthreads();   // accs WAR: A2 reads done before C leader writes

  const float* hidbase = &sm.hidkv[le0][0];

  // ---- Phase C: 9 weight-gen passes, butterfly-reduced, leader-written ----
  // SS: h=0..3, u=r, 8 w
  #pragma unroll 1
  for (int h=0; h<4; ++h){
    float wk[4][8], wv[4][8];
    gemv8<F32>(Wk2, Wv2, bk2, bv2, hidbase, h*576 + r*8, wk, wv);
    #pragma unroll 1
    for (int e=0; e<4; ++e){
      const int le = le0+e;
      const float f = sm.fss[le][r];
      float vals[16];
      #pragma unroll
      for (int q=0; q<8; ++q){ vals[q] = f*wk[e][q]; vals[8+q] = f*wv[e][q]; }
      bfly<16,5>(vals);
      if (r == 0)
        #pragma unroll
        for (int q=0; q<8; ++q){
          sm.accs[le][K0SS + h*8+q] = vals[q];
          sm.accs[le][V0SS + h*8+q] = vals[8+q];
        }
    }
  }
  // VV: 2 passes, half-wave per head
  #pragma unroll 1
  for (int p=0; p<2; ++p){
    const int h = 2*p + (r>>4);
    const int u = r & 15;
    float wk[4][8], wv[4][8];
    gemv8<F32>(Wk2, Wv2, bk2, bv2, hidbase, h*576 + 256 + u*8, wk, wv);
    #pragma unroll 1
    for (int e=0; e<4; ++e){
      const int le = le0+e;
      const float f = sm.fvv[le][u];
      float vals[16];
      #pragma unroll
      for (int q=0; q<8; ++q){ vals[q] = f*wk[e][q]; vals[8+q] = f*wv[e][q]; }
      bfly<16,4>(vals);
      if ((r & 15) == 0)
        #pragma unroll
        for (int q=0; q<8; ++q){
          sm.accs[le][K0VV + h*8+q] = vals[q];
          sm.accs[le][V0VV + h*8+q] = vals[8+q];
        }
    }
  }
  // SV: 2 passes, half-wave per head, lane covers 2 u-rows of 4 w
  #pragma unroll 1
  for (int p=0; p<2; ++p){
    const int h = 2*p + (r>>4);
    const int u0 = (r & 15)*2;
    float wk[4][8], wv[4][8];
    gemv8<F32>(Wk2, Wv2, bk2, bv2, hidbase, h*576 + 384 + u0*4, wk, wv);
    #pragma unroll 1
    for (int e=0; e<4; ++e){
      const int le = le0+e;
      const float f0 = sm.ssl[le][u0], f1 = sm.ssl[le][u0+1];
      float vals[8];
      #pragma unroll
      for (int w=0; w<4; ++w){
        vals[w]   = f0*wk[e][w] + f1*wk[e][4+w];
        vals[4+w] = f0*wv[e][w] + f1*wv[e][4+w];
      }
      bfly<8,4>(vals);
      if ((r & 15) == 0)
        #pragma unroll
        for (int w=0; w<4; ++w){
          sm.accs[le][PSVK + h*4+w] = vals[w];
          sm.accs[le][PSVV + h*4+w] = vals[4+w];
        }
    }
  }
  // VS: 1 pass, 8 lanes per head, lane covers 2 u-rows of 4 w, 3 i each
  {
    const int h = r >> 3;
    const int u0 = (r & 7)*2;
    float wk[4][8], wv[4][8];
    gemv8<F32>(Wk2, Wv2, bk2, bv2, hidbase, h*576 + 512 + u0*4, wk, wv);
    #pragma unroll 1
    for (int e=0; e<4; ++e){
      const int le = le0+e;
      float vals[24];
      #pragma unroll
      for (int w=0; w<4; ++w)
        #pragma unroll
        for (int i=0; i<3; ++i){
          const float fa = sm.vsh[le][u0*3+i], fb = sm.vsh[le][u0*3+3+i];
          vals[w*3+i]    = fa*wk[e][w] + fb*wk[e][4+w];
          vals[12+w*3+i] = fa*wv[e][w] + fb*wv[e][4+w];
        }
      bfly<24,3>(vals);
      if ((r & 7) == 0)
        #pragma unroll
        for (int idx=0; idx<12; ++idx){
          sm.accs[le][VSK + h*12+idx] = vals[idx];
          sm.accs[le][VSV + h*12+idx] = vals[12+idx];
        }
    }
  }
  __syncthreads();

  // ---- Phase D: logits -> exp -> global aggregation (block-wide: 8 threads/edge) ----
  const float invfan = 0.14433756729740643f;   // 1/sqrt(48)
  const int le = t >> 3, sub = t & 7;
  const int d = sm.dstl[le];
  if (sub < 4){
    const int h = sub;
    float lg0 = 0.f;
    #pragma unroll
    for (int w=0; w<8; ++w)
      lg0 += sm.qd0l[le][h*8+w] * (sm.accs[le][K0SS+h*8+w] + sm.accs[le][K0VV+h*8+w]);
    float lg1 = 0.f;
    #pragma unroll
    for (int w=0; w<4; ++w)
      #pragma unroll
      for (int i=0; i<3; ++i){
        float k1 = sm.accs[le][PSVK+h*4+w]*sm.sh1l[le][i] + sm.accs[le][VSK+h*12+w*3+i];
        lg1 += sm.qd1l[le][h*12+w*3+i] * k1;
      }
    float lg = (lg0 + lg1*0.5773502691896258f) * invfan * 0.025f;  // 1/(sqrt(80)*sqrt(20))
    lg = fminf(10.f, fmaxf(-10.f, lg));
    const float exv = __expf(lg - 10.0f);    // fixed softmax max = 10 (logits clipped)
    sm.sh_ex[le][h] = exv;
    atomicAdd(denom + d*4+h, exv);
  }
  __syncthreads();
  for (int idx=sub; idx<80; idx+=8){
    if (idx < 32){
      const int h = idx >> 3;
      const float v0 = (sm.accs[le][V0SS+idx] + sm.accs[le][V0VV+idx]) * invfan;
      atomicAdd(agg0 + d*32 + idx, sm.sh_ex[le][h]*v0);
    } else {
      const int j = idx-32, h = j/12, rem = j - h*12, w = rem/3, i = rem - w*3;
      const float v1 = (sm.accs[le][PSVV+h*4+w]*sm.sh1l[le][i] + sm.accs[le][VSV+j]) * invfan;
      atomicAdd(agg1 + d*48 + j, sm.sh_ex[le][h]*v1);
    }
  }
}

__global__ __launch_bounds__(256) void edge_kernel(
    const void* nf, const int* eidx, const void* esh, const void* emb,
    const void* Wk1, const void* bk1, const void* Wk2, const void* bk2,
    const void* Wv1, const void* bv1, const void* Wv2, const void* bv2,
    const void* Wq0, const void* Wq1, const void* Wd0, const void* Wd1,
    float* agg0, float* agg1, float* denom, const int* flag){
  __shared__ Smem sm;
  if (*flag)
    edge_body<true >(nf,eidx,esh,emb,Wk1,bk1,Wk2,bk2,Wv1,bv1,Wv2,bv2,Wq0,Wq1,Wd0,Wd1,agg0,agg1,denom,sm);
  else
    edge_body<false>(nf,eidx,esh,emb,Wk1,bk1,Wk2,bk2,Wv1,bv1,Wv2,bv2,Wq0,Wq1,Wd0,Wd1,agg0,agg1,denom,sm);
}

// ---------- K2: per-node output MLP ----------
__global__ __launch_bounds__(64) void node_out_kernel(
    const void* __restrict__ nf, const float* __restrict__ agg0r, const float* __restrict__ agg1r,
    const float* __restrict__ denom,
    const void* __restrict__ Wo0, const void* __restrict__ Wo1,
    const void* __restrict__ Wf10, const void* __restrict__ Wf11,
    const void* __restrict__ Wf20, const void* __restrict__ Wf21,
    void* __restrict__ out, const int* __restrict__ flag){
  __shared__ float ag0[32], ag1[48], adiv[4];
  __shared__ float x0s[32], x1s[48], a0s[64], f1s[48], coefs[16];
  const bool F32 = (*flag) != 0;
  const int n = blockIdx.x, t = threadIdx.x;
  if (t < 4) adiv[t] = 1.f / (denom[n*4+t] + 1e-12f);
  __syncthreads();
  if (t < 32) ag0[t] = agg0r[n*32+t] * adiv[t>>3];
  if (t < 48) ag1[t] = agg1r[n*48+t] * adiv[t/12];
  __syncthreads();
  if (t < 32){
    float o = 0.f;
    #pragma unroll
    for (int k=0; k<32; ++k) o += ag0[k]*ldfr(Wo0, k*32+t, F32);
    x0s[t] = ldfr(nf, n*80+t, F32) + o*0.17677669529663687f;
  }
  if (t < 48){
    int w = t/3, i = t - w*3;
    float o = 0.f;
    #pragma unroll
    for (int u=0; u<16; ++u) o += ag1[u*3+i]*ldfr(Wo1, u*16+w, F32);
    x1s[t] = ldfr(nf, n*80+32+t, F32) + o*0.25f;
  }
  __syncthreads();
  {
    float f0 = 0.f;
    #pragma unroll
    for (int u=0; u<32; ++u) f0 += x0s[u]*ldfr(Wf10, u*64+t, F32);
    a0s[t] = siluf(f0*0.17677669529663687f);
  }
  if (t < 48){
    int w = t/3, i = t - w*3;
    float f1 = 0.f;
    #pragma unroll
    for (int u=0; u<16; ++u) f1 += x1s[u*3+i]*ldfr(Wf11, u*16+w, F32);
    f1s[t] = f1*0.25f;
  }
  __syncthreads();
  if (t < 16){
    float a = f1s[t*3], b = f1s[t*3+1], c = f1s[t*3+2];
    float nrm = sqrtf(a*a+b*b+c*c);
    float safe = fmaxf(nrm, 1e-8f);
    coefs[t] = (nrm < 1e-8f) ? 0.f : siluf(nrm)/safe;
  }
  __syncthreads();
  if (t < 32){
    float g = 0.f;
    #pragma unroll
    for (int u=0; u<64; ++u) g += a0s[u]*ldfr(Wf20, u*32+t, F32);
    float val = x0s[t] + g*0.125f;
    if (F32) ((float*)out)[n*80+t] = val; else ((ushort*)out)[n*80+t] = f2b(val);
  }
  if (t < 48){
    int w = t/3, i = t - w*3;
    float g = 0.f;
    #pragma unroll
    for (int u=0; u<16; ++u) g += coefs[u]*f1s[u*3+i]*ldfr(Wf21, u*16+w, F32);
    float val = x1s[t] + g*0.25f;
    if (F32) ((float*)out)[n*80+32+t] = val; else ((ushort*)out)[n*80+32+t] = f2b(val);
  }
}

extern "C" void kernel_launch(void* const* d_in, const int* in_sizes, int n_in,
                              void* d_out, int out_size, void* d_ws, size_t ws_size,
                              hipStream_t stream){
  const void* nf   = d_in[0];
  const int*  eidx = (const int*)d_in[1];
  const void* esh  = d_in[2];
  const void* emb  = d_in[3];
  const void* Wq0  = d_in[4];
  const void* Wq1  = d_in[5];
  const void* Wk1  = d_in[6];
  const void* bk1  = d_in[7];
  const void* Wk2  = d_in[8];
  const void* bk2  = d_in[9];
  const void* Wv1  = d_in[10];
  const void* bv1  = d_in[11];
  const void* Wv2  = d_in[12];
  const void* bv2  = d_in[13];
  const void* Wd0  = d_in[14];
  const void* Wd1  = d_in[15];
  const void* Wo0  = d_in[16];
  const void* Wo1  = d_in[17];
  const void* Wf10 = d_in[18];
  const void* Wf11 = d_in[19];
  const void* Wf20 = d_in[20];
  const void* Wf21 = d_in[21];
  float* ws = (float*)d_ws;

  float* agg0  = ws + OFF_AGG0;
  float* agg1  = ws + OFF_AGG1;
  float* denom = ws + OFF_DEN;
  int*   flag  = (int*)(ws + OFF_FLAG);

  hipMemsetAsync(agg0, 0, (64000+96000+8000)*sizeof(float), stream);
  probe_kernel<<<1, 256, 0, stream>>>((const ushort*)nf, flag);
  edge_kernel<<<N_EDGES/32, 256, 0, stream>>>(nf, eidx, esh, emb, Wk1, bk1, Wk2, bk2,
                                              Wv1, bv1, Wv2, bv2, Wq0, Wq1, Wd0, Wd1,
                                              agg0, agg1, denom, flag);
  node_out_kernel<<<N_NODES, 64, 0, stream>>>(nf, agg0, agg1, denom,
                                              Wo0, Wo1, Wf10, Wf11, Wf20, Wf21, d_out, flag);
}

// Round 5
// 244.236 us; speedup vs baseline: 6.1260x; 2.2856x over previous
//
#include <hip/hip_runtime.h>

typedef unsigned int uint;
typedef unsigned short ushort;
typedef __attribute__((ext_vector_type(8))) short bf16x8;
typedef __attribute__((ext_vector_type(4))) float f32x4;

#define N_NODES 2000
#define N_EDGES 32000
#define WNUM 2304

// ---------- ws layout (float element offsets) — total 315,460 floats = 1.26 MB ----------
constexpr size_t OFF_AGG0 = 0;        // 2000*32
constexpr size_t OFF_AGG1 = 64000;    // 2000*48
constexpr size_t OFF_DEN  = 160000;   // 2000*4
constexpr size_t OFF_FLAG = 168000;   // 1 int
constexpr size_t OFF_W2T  = 168004;   // ushort[2][2304][64] = 294912 ushorts = 147456 floats
                                      // byte offset 672016 (16B aligned)

__device__ __forceinline__ float b2f(ushort u){ union{uint i; float f;}x; x.i=((uint)u)<<16; return x.f; }
__device__ __forceinline__ ushort f2b(float f){
  union{float f; uint u;}x; x.f=f;
  uint r = (x.u + 0x7FFFu + ((x.u>>16)&1u)) >> 16;
  return (ushort)r;
}
__device__ __forceinline__ float siluf(float x){ return x / (1.f + __expf(-x)); }

template<bool F32>
__device__ __forceinline__ float ldf(const void* p, int i){
  if (F32) return ((const float*)p)[i];
  return b2f(((const ushort*)p)[i]);
}
__device__ __forceinline__ float ldfr(const void* p, int i, bool f32){
  return f32 ? ((const float*)p)[i] : b2f(((const ushort*)p)[i]);
}

// ---------- K0: dtype probe ----------
__global__ void probe_kernel(const ushort* __restrict__ nf, int* __restrict__ flag){
  __shared__ int cnt;
  if (threadIdx.x == 0) cnt = 0;
  __syncthreads();
  uint u = nf[threadIdx.x * 2];
  uint ex = (u >> 7) & 0xFFu;
  if (ex >= 0xA0u) atomicAdd(&cnt, 1);
  __syncthreads();
  if (threadIdx.x == 0) *flag = (cnt >= 20) ? 1 : 0;
}

// ---------- K1: W2 transpose -> W2T[mat][j][c] bf16 (B-frag friendly) ----------
__global__ __launch_bounds__(256) void w2t_kernel(const void* __restrict__ Wk2,
                                                  const void* __restrict__ Wv2,
                                                  ushort* __restrict__ W2T,
                                                  const int* __restrict__ flag){
  const bool F32 = (*flag) != 0;
  int id = blockIdx.x*256 + threadIdx.x;      // 0 .. 294912
  int mat = id / 147456;
  int rem = id - mat*147456;
  int c = rem & 63, j = rem >> 6;
  const void* W = mat ? Wv2 : Wk2;
  float v = F32 ? ((const float*)W)[c*WNUM + j] : b2f(((const ushort*)W)[c*WNUM + j]);
  W2T[id] = f2b(v);
}

// ---------- K2: fused edge kernel (MFMA weight-gen) ----------
// Block = 256 thr = 4 waves, 32 edges. Wave w computes head w's 36 N-tiles.
// GEMM: A = hid[32 edges][64 c] (bf16, LDS), B = W2T tiles, C init = bias.
// TP contraction fused per tile in MFMA C-layout (col=lane&15 -> j, row=quad*4+reg -> edge).
struct Smem {
  ushort hidA[2][32][64];     // [kv][edge][c] bf16   8 KB
  float fssT[32][32];         // [u][e] ss*sh0        4 KB
  float fvvT[16][32];         // [u][e] vv.sh1/√3     2 KB
  float sslT[32][32];         // [u][e] ss            4 KB
  float vshT[16][3][32];      // [u][i][e] vv*sh0     6 KB
  float qd0T[4][8][32];       // [h][w][e]            4 KB
  float qd1T[4][4][3][32];    // [h][w4][i][e]        6 KB
  float sh1T[3][32];          // [i][e]               384 B
  float dstF[32][80];         // dst node feats       10 KB
  int   dstL[32];
};                            // ~45.6 KB

template<bool F32>
__device__ void edge_body(
    const void* __restrict__ nf,  const int* __restrict__ eidx,
    const void* __restrict__ esh, const void* __restrict__ emb,
    const void* __restrict__ Wk1, const void* __restrict__ bk1, const void* __restrict__ bk2,
    const void* __restrict__ Wv1, const void* __restrict__ bv1, const void* __restrict__ bv2,
    const void* __restrict__ Wq0, const void* __restrict__ Wq1,
    const void* __restrict__ Wd0, const void* __restrict__ Wd1,
    const ushort* __restrict__ W2T,
    float* __restrict__ agg0, float* __restrict__ agg1, float* __restrict__ denom,
    Smem& sm){
  const int t  = threadIdx.x;
  const int hw = t >> 5;        // half-wave 0..7
  const int r  = t & 31;
  const int geb = blockIdx.x*32;

  // ---- Phase A: per-edge features (4 edges per half-wave) ----
  #pragma unroll 1
  for (int e=0; e<4; ++e){
    const int le = hw*4+e, ge = geb+le;
    const int src = eidx[ge], d = eidx[N_EDGES+ge];
    const float sh0 = ldf<F32>(esh, ge*4+0);
    const float s1a = ldf<F32>(esh, ge*4+1), s1b = ldf<F32>(esh, ge*4+2), s1c = ldf<F32>(esh, ge*4+3);
    if (r == 0) sm.dstL[le] = d;
    if (r < 3) sm.sh1T[r][le] = (r==0)? s1a : (r==1)? s1b : s1c;
    float sv = ldf<F32>(nf, src*80 + r);
    sm.sslT[r][le] = sv;
    sm.fssT[r][le] = sv * sh0;
    sm.dstF[le][r] = ldf<F32>(nf, d*80 + r);
    if (r < 16){
      float v0 = ldf<F32>(nf, src*80+32+r*3+0);
      float v1 = ldf<F32>(nf, src*80+32+r*3+1);
      float v2 = ldf<F32>(nf, src*80+32+r*3+2);
      sm.vshT[r][0][le] = v0*sh0; sm.vshT[r][1][le] = v1*sh0; sm.vshT[r][2][le] = v2*sh0;
      sm.fvvT[r][le] = (v0*s1a + v1*s1b + v2*s1c) * 0.5773502691896258f;
      sm.dstF[le][32+r*3+0] = ldf<F32>(nf, d*80+32+r*3+0);
      sm.dstF[le][32+r*3+1] = ldf<F32>(nf, d*80+32+r*3+1);
      sm.dstF[le][32+r*3+2] = ldf<F32>(nf, d*80+32+r*3+2);
    }
  }

  // ---- Phase A2: dst q with Wd folded -> qd0T, qd1T ----
  #pragma unroll 1
  for (int e=0; e<4; ++e){
    const int le = hw*4+e;
    const int h8 = r & 24, w8 = r & 7;
    float a = 0.f;
    #pragma unroll
    for (int u=0; u<32; ++u) a += sm.dstF[le][u] * ldf<F32>(Wq0, (r>>3)*256 + u*8 + w8);
    const float q0 = a * 0.17677669529663687f;    // 1/sqrt(32)
    float qd0 = 0.f;
    #pragma unroll
    for (int u=0; u<8; ++u) qd0 += __shfl(q0, h8+u, 32) * ldf<F32>(Wd0, u*8 + w8);
    sm.qd0T[r>>3][w8][le] = qd0;

    const int rr = r & 15, h4 = rr>>2, w4 = rr&3;
    float q1i[3];
    #pragma unroll
    for (int i=0; i<3; ++i){
      float b = 0.f;
      #pragma unroll
      for (int u=0; u<16; ++u) b += sm.dstF[le][32+u*3+i] * ldf<F32>(Wq1, h4*64 + u*4 + w4);
      q1i[i] = b * 0.25f;       // 1/sqrt(16)
    }
    #pragma unroll
    for (int i=0; i<3; ++i){
      float b = 0.f;
      #pragma unroll
      for (int u=0; u<4; ++u) b += __shfl(q1i[i], h4*4+u, 32) * ldf<F32>(Wd1, u*4 + w4);
      if (r < 16) sm.qd1T[h4][w4][i][le] = b;
    }
  }

  // ---- Phase B: radial-MLP hidden layers -> hidA (bf16) ----
  #pragma unroll 1
  for (int e=0; e<4; ++e){
    const int le = hw*4+e, ge = geb+le;
    float em[16];
    #pragma unroll
    for (int b=0; b<16; ++b) em[b] = ldf<F32>(emb, ge*16 + b);
    #pragma unroll
    for (int cc=0; cc<2; ++cc){
      const int c = r + cc*32;
      float ak = ldf<F32>(bk1, c), av = ldf<F32>(bv1, c);
      #pragma unroll
      for (int b=0; b<16; ++b){
        ak += em[b] * ldf<F32>(Wk1, b*64 + c);
        av += em[b] * ldf<F32>(Wv1, b*64 + c);
      }
      sm.hidA[0][le][c] = f2b(siluf(ak));
      sm.hidA[1][le][c] = f2b(siluf(av));
    }
  }
  __syncthreads();

  // ---- Phase C: per-wave MFMA tile loop (wave = head) ----
  const int h = t >> 6;           // head
  const int lane = t & 63, q = lane >> 4, n = lane & 15;
  const ushort* w2tk = W2T;
  const ushort* w2tv = W2T + 147456;

  bf16x8 af[2][2][2];             // [kv][Mt][Khalf]
  #pragma unroll
  for (int kv=0; kv<2; ++kv)
    #pragma unroll
    for (int Mt=0; Mt<2; ++Mt)
      #pragma unroll
      for (int kh=0; kh<2; ++kh)
        af[kv][Mt][kh] = *(const bf16x8*)&sm.hidA[kv][Mt*16+n][kh*32 + q*8];

  float aK0[2][4], aV0[2][4], aPK[2][4], aPV[2][4], aWK[3][2][4], aWV[3][2][4];
  #pragma unroll
  for (int Mt=0; Mt<2; ++Mt)
    #pragma unroll
    for (int z=0; z<4; ++z){
      aK0[Mt][z]=0.f; aV0[Mt][z]=0.f; aPK[Mt][z]=0.f; aPV[Mt][z]=0.f;
      aWK[0][Mt][z]=0.f; aWK[1][Mt][z]=0.f; aWK[2][Mt][z]=0.f;
      aWV[0][Mt][z]=0.f; aWV[1][Mt][z]=0.f; aWV[2][Mt][z]=0.f;
    }

  // ss tiles 0..15: u = tl*2 + (n>>3), w = n&7 -> aK0/aV0
  #pragma unroll 2
  for (int tl=0; tl<16; ++tl){
    const size_t tb = ((size_t)((h*36+tl)*16 + n))*64 + q*8;
    bf16x8 bk0 = *(const bf16x8*)(w2tk + tb), bk1f = *(const bf16x8*)(w2tk + tb + 32);
    bf16x8 bv0 = *(const bf16x8*)(w2tv + tb), bv1f = *(const bf16x8*)(w2tv + tb + 32);
    const int j = h*576 + tl*16 + n;
    const float bbk = ldf<F32>(bk2, j), bbv = ldf<F32>(bv2, j);
    const int u = tl*2 + (n>>3);
    #pragma unroll
    for (int Mt=0; Mt<2; ++Mt){
      f32x4 fv = *(const f32x4*)&sm.fssT[u][Mt*16+q*4];
      f32x4 ck = {bbk,bbk,bbk,bbk};
      ck = __builtin_amdgcn_mfma_f32_16x16x32_bf16(af[0][Mt][0], bk0, ck, 0,0,0);
      ck = __builtin_amdgcn_mfma_f32_16x16x32_bf16(af[0][Mt][1], bk1f, ck, 0,0,0);
      f32x4 cv = {bbv,bbv,bbv,bbv};
      cv = __builtin_amdgcn_mfma_f32_16x16x32_bf16(af[1][Mt][0], bv0, cv, 0,0,0);
      cv = __builtin_amdgcn_mfma_f32_16x16x32_bf16(af[1][Mt][1], bv1f, cv, 0,0,0);
      #pragma unroll
      for (int z=0; z<4; ++z){ aK0[Mt][z] += ck[z]*fv[z]; aV0[Mt][z] += cv[z]*fv[z]; }
    }
  }
  // vv tiles 16..23: u = (tl-16)*2 + (n>>3) -> aK0/aV0
  #pragma unroll 2
  for (int tl=16; tl<24; ++tl){
    const size_t tb = ((size_t)((h*36+tl)*16 + n))*64 + q*8;
    bf16x8 bk0 = *(const bf16x8*)(w2tk + tb), bk1f = *(const bf16x8*)(w2tk + tb + 32);
    bf16x8 bv0 = *(const bf16x8*)(w2tv + tb), bv1f = *(const bf16x8*)(w2tv + tb + 32);
    const int j = h*576 + tl*16 + n;
    const float bbk = ldf<F32>(bk2, j), bbv = ldf<F32>(bv2, j);
    const int u = (tl-16)*2 + (n>>3);
    #pragma unroll
    for (int Mt=0; Mt<2; ++Mt){
      f32x4 fv = *(const f32x4*)&sm.fvvT[u][Mt*16+q*4];
      f32x4 ck = {bbk,bbk,bbk,bbk};
      ck = __builtin_amdgcn_mfma_f32_16x16x32_bf16(af[0][Mt][0], bk0, ck, 0,0,0);
      ck = __builtin_amdgcn_mfma_f32_16x16x32_bf16(af[0][Mt][1], bk1f, ck, 0,0,0);
      f32x4 cv = {bbv,bbv,bbv,bbv};
      cv = __builtin_amdgcn_mfma_f32_16x16x32_bf16(af[1][Mt][0], bv0, cv, 0,0,0);
      cv = __builtin_amdgcn_mfma_f32_16x16x32_bf16(af[1][Mt][1], bv1f, cv, 0,0,0);
      #pragma unroll
      for (int z=0; z<4; ++z){ aK0[Mt][z] += ck[z]*fv[z]; aV0[Mt][z] += cv[z]*fv[z]; }
    }
  }
  // sv tiles 24..31: u = (tl-24)*4 + (n>>2), w4 = n&3 -> aPK/aPV
  #pragma unroll 2
  for (int tl=24; tl<32; ++tl){
    const size_t tb = ((size_t)((h*36+tl)*16 + n))*64 + q*8;
    bf16x8 bk0 = *(const bf16x8*)(w2tk + tb), bk1f = *(const bf16x8*)(w2tk + tb + 32);
    bf16x8 bv0 = *(const bf16x8*)(w2tv + tb), bv1f = *(const bf16x8*)(w2tv + tb + 32);
    const int j = h*576 + tl*16 + n;
    const float bbk = ldf<F32>(bk2, j), bbv = ldf<F32>(bv2, j);
    const int u = (tl-24)*4 + (n>>2);
    #pragma unroll
    for (int Mt=0; Mt<2; ++Mt){
      f32x4 fv = *(const f32x4*)&sm.sslT[u][Mt*16+q*4];
      f32x4 ck = {bbk,bbk,bbk,bbk};
      ck = __builtin_amdgcn_mfma_f32_16x16x32_bf16(af[0][Mt][0], bk0, ck, 0,0,0);
      ck = __builtin_amdgcn_mfma_f32_16x16x32_bf16(af[0][Mt][1], bk1f, ck, 0,0,0);
      f32x4 cv = {bbv,bbv,bbv,bbv};
      cv = __builtin_amdgcn_mfma_f32_16x16x32_bf16(af[1][Mt][0], bv0, cv, 0,0,0);
      cv = __builtin_amdgcn_mfma_f32_16x16x32_bf16(af[1][Mt][1], bv1f, cv, 0,0,0);
      #pragma unroll
      for (int z=0; z<4; ++z){ aPK[Mt][z] += ck[z]*fv[z]; aPV[Mt][z] += cv[z]*fv[z]; }
    }
  }
  // vs tiles 32..35: u = (tl-32)*4 + (n>>2), w4 = n&3 -> aWK[i]/aWV[i]
  #pragma unroll 1
  for (int tl=32; tl<36; ++tl){
    const size_t tb = ((size_t)((h*36+tl)*16 + n))*64 + q*8;
    bf16x8 bk0 = *(const bf16x8*)(w2tk + tb), bk1f = *(const bf16x8*)(w2tk + tb + 32);
    bf16x8 bv0 = *(const bf16x8*)(w2tv + tb), bv1f = *(const bf16x8*)(w2tv + tb + 32);
    const int j = h*576 + tl*16 + n;
    const float bbk = ldf<F32>(bk2, j), bbv = ldf<F32>(bv2, j);
    const int u = (tl-32)*4 + (n>>2);
    #pragma unroll
    for (int Mt=0; Mt<2; ++Mt){
      f32x4 ck = {bbk,bbk,bbk,bbk};
      ck = __builtin_amdgcn_mfma_f32_16x16x32_bf16(af[0][Mt][0], bk0, ck, 0,0,0);
      ck = __builtin_amdgcn_mfma_f32_16x16x32_bf16(af[0][Mt][1], bk1f, ck, 0,0,0);
      f32x4 cv = {bbv,bbv,bbv,bbv};
      cv = __builtin_amdgcn_mfma_f32_16x16x32_bf16(af[1][Mt][0], bv0, cv, 0,0,0);
      cv = __builtin_amdgcn_mfma_f32_16x16x32_bf16(af[1][Mt][1], bv1f, cv, 0,0,0);
      #pragma unroll
      for (int i=0; i<3; ++i){
        f32x4 fv = *(const f32x4*)&sm.vshT[u][i][Mt*16+q*4];
        #pragma unroll
        for (int z=0; z<4; ++z){ aWK[i][Mt][z] += ck[z]*fv[z]; aWV[i][Mt][z] += cv[z]*fv[z]; }
      }
    }
  }

  // ---- cross-lane u-reductions ----
  #pragma unroll
  for (int Mt=0; Mt<2; ++Mt)
    #pragma unroll
    for (int z=0; z<4; ++z){
      aK0[Mt][z] += __shfl_xor(aK0[Mt][z], 8, 64);
      aV0[Mt][z] += __shfl_xor(aV0[Mt][z], 8, 64);
      aPK[Mt][z] += __shfl_xor(aPK[Mt][z], 4, 64);
      aPK[Mt][z] += __shfl_xor(aPK[Mt][z], 8, 64);
      aPV[Mt][z] += __shfl_xor(aPV[Mt][z], 4, 64);
      aPV[Mt][z] += __shfl_xor(aPV[Mt][z], 8, 64);
      #pragma unroll
      for (int i=0; i<3; ++i){
        aWK[i][Mt][z] += __shfl_xor(aWK[i][Mt][z], 4, 64);
        aWK[i][Mt][z] += __shfl_xor(aWK[i][Mt][z], 8, 64);
        aWV[i][Mt][z] += __shfl_xor(aWV[i][Mt][z], 4, 64);
        aWV[i][Mt][z] += __shfl_xor(aWV[i][Mt][z], 8, 64);
      }
    }

  // ---- Phase D: logits -> exp -> global aggregation (wave-internal) ----
  const float invfan = 0.14433756729740643f;   // 1/sqrt(48)
  f32x4 s1v[3][2];
  #pragma unroll
  for (int i=0; i<3; ++i)
    #pragma unroll
    for (int Mt=0; Mt<2; ++Mt)
      s1v[i][Mt] = *(const f32x4*)&sm.sh1T[i][Mt*16+q*4];

  float lgp[2][4];
  #pragma unroll
  for (int Mt=0; Mt<2; ++Mt){
    f32x4 qd0v = *(const f32x4*)&sm.qd0T[h][n&7][Mt*16+q*4];
    #pragma unroll
    for (int z=0; z<4; ++z){
      float acc = (n < 8) ? qd0v[z]*aK0[Mt][z] : 0.f;
      if (n < 4){
        float s = 0.f;
        #pragma unroll
        for (int i=0; i<3; ++i){
          f32x4 qd1v = *(const f32x4*)&sm.qd1T[h][n&3][i][Mt*16+q*4];
          float k1 = aPK[Mt][z]*s1v[i][Mt][z] + aWK[i][Mt][z];
          s += qd1v[z]*k1;
        }
        acc += s * 0.5773502691896258f;
      }
      lgp[Mt][z] = acc;
    }
  }
  #pragma unroll
  for (int Mt=0; Mt<2; ++Mt)
    #pragma unroll
    for (int z=0; z<4; ++z){
      lgp[Mt][z] += __shfl_xor(lgp[Mt][z], 1, 64);
      lgp[Mt][z] += __shfl_xor(lgp[Mt][z], 2, 64);
      lgp[Mt][z] += __shfl_xor(lgp[Mt][z], 4, 64);
      lgp[Mt][z] += __shfl_xor(lgp[Mt][z], 8, 64);
    }

  float exv[2][4]; int dn[2][4];
  #pragma unroll
  for (int Mt=0; Mt<2; ++Mt)
    #pragma unroll
    for (int z=0; z<4; ++z){
      float lg = lgp[Mt][z] * invfan * 0.025f;   // 1/(sqrt(80)*sqrt(20))
      lg = fminf(10.f, fmaxf(-10.f, lg));
      exv[Mt][z] = __expf(lg - 10.0f);           // fixed softmax max = 10 (clipped logits)
      dn[Mt][z] = sm.dstL[Mt*16 + q*4 + z];
    }

  if (n == 0){
    #pragma unroll
    for (int Mt=0; Mt<2; ++Mt)
      #pragma unroll
      for (int z=0; z<4; ++z)
        atomicAdd(denom + dn[Mt][z]*4 + h, exv[Mt][z]);
  }
  if (n < 8){
    #pragma unroll
    for (int Mt=0; Mt<2; ++Mt)
      #pragma unroll
      for (int z=0; z<4; ++z)
        atomicAdd(agg0 + dn[Mt][z]*32 + h*8 + n, exv[Mt][z]*aV0[Mt][z]*invfan);
  }
  if (n < 4){
    #pragma unroll
    for (int i=0; i<3; ++i)
      #pragma unroll
      for (int Mt=0; Mt<2; ++Mt)
        #pragma unroll
        for (int z=0; z<4; ++z){
          float v1 = (aPV[Mt][z]*s1v[i][Mt][z] + aWV[i][Mt][z]) * invfan;
          atomicAdd(agg1 + dn[Mt][z]*48 + h*12 + n*3 + i, exv[Mt][z]*v1);
        }
  }
}

__global__ __launch_bounds__(256) void edge_kernel(
    const void* nf, const int* eidx, const void* esh, const void* emb,
    const void* Wk1, const void* bk1, const void* bk2,
    const void* Wv1, const void* bv1, const void* bv2,
    const void* Wq0, const void* Wq1, const void* Wd0, const void* Wd1,
    const ushort* W2T, float* agg0, float* agg1, float* denom, const int* flag){
  __shared__ Smem sm;
  if (*flag)
    edge_body<true >(nf,eidx,esh,emb,Wk1,bk1,bk2,Wv1,bv1,bv2,Wq0,Wq1,Wd0,Wd1,W2T,agg0,agg1,denom,sm);
  else
    edge_body<false>(nf,eidx,esh,emb,Wk1,bk1,bk2,Wv1,bv1,bv2,Wq0,Wq1,Wd0,Wd1,W2T,agg0,agg1,denom,sm);
}

// ---------- K3: per-node output MLP ----------
__global__ __launch_bounds__(64) void node_out_kernel(
    const void* __restrict__ nf, const float* __restrict__ agg0r, const float* __restrict__ agg1r,
    const float* __restrict__ denom,
    const void* __restrict__ Wo0, const void* __restrict__ Wo1,
    const void* __restrict__ Wf10, const void* __restrict__ Wf11,
    const void* __restrict__ Wf20, const void* __restrict__ Wf21,
    void* __restrict__ out, const int* __restrict__ flag){
  __shared__ float ag0[32], ag1[48], adiv[4];
  __shared__ float x0s[32], x1s[48], a0s[64], f1s[48], coefs[16];
  const bool F32 = (*flag) != 0;
  const int n = blockIdx.x, t = threadIdx.x;
  if (t < 4) adiv[t] = 1.f / (denom[n*4+t] + 1e-12f);
  __syncthreads();
  if (t < 32) ag0[t] = agg0r[n*32+t] * adiv[t>>3];
  if (t < 48) ag1[t] = agg1r[n*48+t] * adiv[t/12];
  __syncthreads();
  if (t < 32){
    float o = 0.f;
    #pragma unroll
    for (int k=0; k<32; ++k) o += ag0[k]*ldfr(Wo0, k*32+t, F32);
    x0s[t] = ldfr(nf, n*80+t, F32) + o*0.17677669529663687f;
  }
  if (t < 48){
    int w = t/3, i = t - w*3;
    float o = 0.f;
    #pragma unroll
    for (int u=0; u<16; ++u) o += ag1[u*3+i]*ldfr(Wo1, u*16+w, F32);
    x1s[t] = ldfr(nf, n*80+32+t, F32) + o*0.25f;
  }
  __syncthreads();
  {
    float f0 = 0.f;
    #pragma unroll
    for (int u=0; u<32; ++u) f0 += x0s[u]*ldfr(Wf10, u*64+t, F32);
    a0s[t] = siluf(f0*0.17677669529663687f);
  }
  if (t < 48){
    int w = t/3, i = t - w*3;
    float f1 = 0.f;
    #pragma unroll
    for (int u=0; u<16; ++u) f1 += x1s[u*3+i]*ldfr(Wf11, u*16+w, F32);
    f1s[t] = f1*0.25f;
  }
  __syncthreads();
  if (t < 16){
    float a = f1s[t*3], b = f1s[t*3+1], c = f1s[t*3+2];
    float nrm = sqrtf(a*a+b*b+c*c);
    float safe = fmaxf(nrm, 1e-8f);
    coefs[t] = (nrm < 1e-8f) ? 0.f : siluf(nrm)/safe;
  }
  __syncthreads();
  if (t < 32){
    float g = 0.f;
    #pragma unroll
    for (int u=0; u<64; ++u) g += a0s[u]*ldfr(Wf20, u*32+t, F32);
    float val = x0s[t] + g*0.125f;
    if (F32) ((float*)out)[n*80+t] = val; else ((ushort*)out)[n*80+t] = f2b(val);
  }
  if (t < 48){
    int w = t/3, i = t - w*3;
    float g = 0.f;
    #pragma unroll
    for (int u=0; u<16; ++u) g += coefs[u]*f1s[u*3+i]*ldfr(Wf21, u*16+w, F32);
    float val = x1s[t] + g*0.25f;
    if (F32) ((float*)out)[n*80+32+t] = val; else ((ushort*)out)[n*80+32+t] = f2b(val);
  }
}

extern "C" void kernel_launch(void* const* d_in, const int* in_sizes, int n_in,
                              void* d_out, int out_size, void* d_ws, size_t ws_size,
                              hipStream_t stream){
  const void* nf   = d_in[0];
  const int*  eidx = (const int*)d_in[1];
  const void* esh  = d_in[2];
  const void* emb  = d_in[3];
  const void* Wq0  = d_in[4];
  const void* Wq1  = d_in[5];
  const void* Wk1  = d_in[6];
  const void* bk1  = d_in[7];
  const void* Wk2  = d_in[8];
  const void* bk2  = d_in[9];
  const void* Wv1  = d_in[10];
  const void* bv1  = d_in[11];
  const void* Wv2  = d_in[12];
  const void* bv2  = d_in[13];
  const void* Wd0  = d_in[14];
  const void* Wd1  = d_in[15];
  const void* Wo0  = d_in[16];
  const void* Wo1  = d_in[17];
  const void* Wf10 = d_in[18];
  const void* Wf11 = d_in[19];
  const void* Wf20 = d_in[20];
  const void* Wf21 = d_in[21];
  float* ws = (float*)d_ws;

  float* agg0  = ws + OFF_AGG0;
  float* agg1  = ws + OFF_AGG1;
  float* denom = ws + OFF_DEN;
  int*   flag  = (int*)(ws + OFF_FLAG);
  ushort* W2T  = (ushort*)(ws + OFF_W2T);

  hipMemsetAsync(agg0, 0, (64000+96000+8000)*sizeof(float), stream);
  probe_kernel<<<1, 256, 0, stream>>>((const ushort*)nf, flag);
  w2t_kernel<<<1152, 256, 0, stream>>>(Wk2, Wv2, W2T, flag);
  edge_kernel<<<N_EDGES/32, 256, 0, stream>>>(nf, eidx, esh, emb,
                                              Wk1, bk1, bk2, Wv1, bv1, bv2,
                                              Wq0, Wq1, Wd0, Wd1, W2T,
                                              agg0, agg1, denom, flag);
  node_out_kernel<<<N_NODES, 64, 0, stream>>>(nf, agg0, agg1, denom,
                                              Wo0, Wo1, Wf10, Wf11, Wf20, Wf21, d_out, flag);
}